// Round 3
// baseline (1857.496 us; speedup 1.0000x reference)
//
#include <hip/hip_runtime.h>
#include <math.h>

// Problem constants
#define NN 8
#define CH 256
#define HH 64
#define WW 64
#define AA 27
#define KK 100
#define MM (HH * WW * AA)   // 110592 per image

// ---------------------------------------------------------------------------
// 3x3 conv + bias + relu, fp32, NCHW, pad=1. C=256 -> 256.
// Block tile: 16 rows x 64 cols x 16 couts. Thread: 4 rows x 16 couts.
// Grid: N * (H/16) * (Cout/16) = 8*4*16 = 512 blocks of 256 threads.
// ---------------------------------------------------------------------------
__global__ __launch_bounds__(256, 2)
void conv3x3_relu(const float* __restrict__ in, const float* __restrict__ wgt,
                  const float* __restrict__ bias, float* __restrict__ out)
{
    __shared__ float s_in[4][18][66];   // [cin][row+halo][col+halo]
    __shared__ float s_w[4][9][16];     // [cin][tap][cout]

    const int tid = threadIdx.x;
    const int bid = blockIdx.x;
    const int co0 = (bid & 15) << 4;        // cout tile base
    const int h0  = ((bid >> 4) & 3) << 4;  // row tile base
    const int n   = bid >> 6;

    const int c  = tid & 63;   // column 0..63
    const int rb = tid >> 6;   // row group 0..3 -> rows rb*4 .. rb*4+3

    float4 acc[4][4];          // [s: 4 rows][g: 4 cout-quads]
#pragma unroll
    for (int s = 0; s < 4; ++s)
#pragma unroll
        for (int g = 0; g < 4; ++g) acc[s][g] = make_float4(0.f, 0.f, 0.f, 0.f);

    for (int chb = 0; chb < 64; ++chb) {   // cin chunks of 4
        const int ci0 = chb << 2;
        __syncthreads();
        // stage input tile with halo (zero-padded)
        for (int i = tid; i < 4 * 18 * 66; i += 256) {
            int cc = i % 66;
            int t2 = i / 66;
            int rr = t2 % 18;
            int ci = t2 / 18;
            int gh = h0 + rr - 1, gc = cc - 1;
            float v = 0.f;
            if ((unsigned)gh < 64u && (unsigned)gc < 64u)
                v = in[(((size_t)n * CH + ci0 + ci) << 12) + (gh << 6) + gc];
            s_in[ci][rr][cc] = v;
        }
        // stage weights reorganized [cin][tap][cout]
        for (int i = tid; i < 4 * 9 * 16; i += 256) {
            int co  = i & 15;
            int t2  = i >> 4;
            int tap = t2 % 9;
            int ci  = t2 / 9;
            s_w[ci][tap][co] = wgt[((size_t)(co0 + co) * CH + ci0 + ci) * 9 + tap];
        }
        __syncthreads();

#pragma unroll
        for (int ci = 0; ci < 4; ++ci) {
            float iv[6][3];   // 6 rows x 3 cols window band shared by the 4 output rows
#pragma unroll
            for (int dy = 0; dy < 6; ++dy)
#pragma unroll
                for (int dx = 0; dx < 3; ++dx)
                    iv[dy][dx] = s_in[ci][rb * 4 + dy][c + dx];
#pragma unroll
            for (int g = 0; g < 4; ++g) {
#pragma unroll
                for (int tap = 0; tap < 9; ++tap) {
                    float4 wv = *(const float4*)&s_w[ci][tap][g * 4];
                    int dy = tap / 3, dx = tap % 3;
#pragma unroll
                    for (int s = 0; s < 4; ++s) {
                        float a = iv[s + dy][dx];
                        acc[s][g].x += a * wv.x;
                        acc[s][g].y += a * wv.y;
                        acc[s][g].z += a * wv.z;
                        acc[s][g].w += a * wv.w;
                    }
                }
            }
        }
    }

    // epilogue: bias + relu + store
#pragma unroll
    for (int g = 0; g < 4; ++g) {
        float b0 = bias[co0 + g * 4 + 0];
        float b1 = bias[co0 + g * 4 + 1];
        float b2 = bias[co0 + g * 4 + 2];
        float b3 = bias[co0 + g * 4 + 3];
#pragma unroll
        for (int s = 0; s < 4; ++s) {
            int h = h0 + rb * 4 + s;
            size_t base = (((size_t)n * CH + co0 + g * 4) << 12) + (h << 6) + c;
            out[base            ] = fmaxf(acc[s][g].x + b0, 0.f);
            out[base + (1 << 12)] = fmaxf(acc[s][g].y + b1, 0.f);
            out[base + (2 << 12)] = fmaxf(acc[s][g].z + b2, 0.f);
            out[base + (3 << 12)] = fmaxf(acc[s][g].w + b3, 0.f);
        }
    }
}

// ---------------------------------------------------------------------------
// Fused 1x1 convs: 135 output channels (27 logits + 108 deltas).
// Block: (n, 64-pixel tile). Thread: 1 pixel x up-to-34 couts.
// tmp layout: [n][135][4096]
// ---------------------------------------------------------------------------
__global__ __launch_bounds__(256, 2)
void conv1x1_kernel(const float* __restrict__ feat, const float* __restrict__ wc,
                    const float* __restrict__ bc, const float* __restrict__ wb,
                    const float* __restrict__ bb, float* __restrict__ tmp)
{
    __shared__ float s_f[64][64];    // [cin][pixel]
    __shared__ float s_w[64][137];   // [cin][cout] padded

    const int tid  = threadIdx.x;
    const int n    = blockIdx.x >> 6;
    const int px0  = (blockIdx.x & 63) << 6;
    const int lane = tid & 63;
    const int g    = tid >> 6;       // cout group 0..3

    float acc[34];
#pragma unroll
    for (int k = 0; k < 34; ++k) acc[k] = 0.f;

    for (int chb = 0; chb < 4; ++chb) {   // cin chunks of 64
        const int ci0 = chb << 6;
        __syncthreads();
        for (int i = tid; i < 64 * 64; i += 256) {
            int ci = i >> 6, pp = i & 63;
            s_f[ci][pp] = feat[(((size_t)n * CH + ci0 + ci) << 12) + px0 + pp];
        }
        for (int i = tid; i < 135 * 64; i += 256) {
            int co = i >> 6, ci = i & 63;
            float w = (co < 27) ? wc[(size_t)co * CH + ci0 + ci]
                                : wb[(size_t)(co - 27) * CH + ci0 + ci];
            s_w[ci][co] = w;
        }
        __syncthreads();
        for (int ci = 0; ci < 64; ++ci) {
            float f = s_f[ci][lane];
#pragma unroll
            for (int k = 0; k < 34; ++k) {
                int co = g * 34 + k;
                acc[k] += f * s_w[ci][co < 135 ? co : 134];
            }
        }
    }
#pragma unroll
    for (int k = 0; k < 34; ++k) {
        int co = g * 34 + k;
        if (co < 135) {
            float b = (co < 27) ? bc[co] : bb[co - 27];
            tmp[((size_t)n * 135 + co) * 4096 + px0 + lane] = acc[k] + b;
        }
    }
}

// ---------------------------------------------------------------------------
// Anchor generation + apply_deltas + validity + score masking.
// Grid: (432, 8) blocks of 256. i indexes (a,p) with a = i/4096, p = i%4096.
// m = p*27 + a matches reference flattening h*W*A + w*A + a.
// ---------------------------------------------------------------------------
__global__ void boxes_kernel(const float* __restrict__ tmp,
                             float* __restrict__ scores, float* __restrict__ boxes)
{
    const int n = blockIdx.y;
    const int i = blockIdx.x * 256 + threadIdx.x;   // < 110592 exactly
    const int a = i >> 12;
    const int p = i & 4095;

    const float* t = tmp + (size_t)n * 135 * 4096;
    float logit = t[(size_t)a * 4096 + p];
    float d0 = t[((size_t)(27 + a * 4 + 0)) * 4096 + p];
    float d1 = t[((size_t)(27 + a * 4 + 1)) * 4096 + p];
    float d2 = t[((size_t)(27 + a * 4 + 2)) * 4096 + p];
    float d3 = t[((size_t)(27 + a * 4 + 3)) * 4096 + p];

    const int hh = p >> 6, ww = p & 63;
    const int si = a / 9, ri = (a / 3) % 3, sci = a % 3;

    double s  = (si == 0) ? 32.0 : (si == 1 ? 64.0 : 128.0);
    double r  = (ri == 0) ? 0.5 : (ri == 1 ? 1.0 : 2.0);
    double sv = (sci == 0) ? 1.0 : (sci == 1 ? pow(2.0, 1.0 / 3.0) : pow(2.0, 2.0 / 3.0));
    double sq = sqrt(r);
    float wa = (float)fmax(s * sv * sq, 1.0);
    float ha = (float)fmax(s * sv / sq, 1.0);
    float bx1 = -0.5f * wa, by1 = -0.5f * ha, bx2 = 0.5f * wa, by2 = 0.5f * ha;

    float sx = ((float)ww + 0.5f) * 4.0f;
    float sy = ((float)hh + 0.5f) * 4.0f;
    float ax1 = fmaxf(bx1 + sx, 0.f);
    float ay1 = fmaxf(by1 + sy, 0.f);
    float ax2 = fminf(fmaxf(bx2 + sx, 0.f), 256.f);
    float ay2 = fminf(fmaxf(by2 + sy, 0.f), 256.f);

    float wdt = ax2 - ax1, hgt = ay2 - ay1;
    float cx = ax1 + 0.5f * wdt, cy = ay1 + 0.5f * hgt;
    float dx = d0 / 10.f, dy = d1 / 10.f, dw = d2 / 5.f, dh = d3 / 5.f;
    float pcx = dx * wdt + cx, pcy = dy * hgt + cy;
    float pw = fmaxf(expf(dw) * wdt, 1.f);
    float ph = fmaxf(expf(dh) * hgt, 1.f);
    float x1 = fminf(fmaxf(pcx - 0.5f * pw, 0.f), 256.f);
    float y1 = fminf(fmaxf(pcy - 0.5f * ph, 0.f), 256.f);
    float x2 = fminf(fmaxf(pcx + 0.5f * pw, 0.f), 256.f);
    float y2 = fminf(fmaxf(pcy + 0.5f * ph, 0.f), 256.f);

    bool inval = ((x2 - x1) < 1.f) || ((y2 - y1) < 1.f);
    float fx1 = inval ? ax1 : x1, fy1 = inval ? ay1 : y1;
    float fx2 = inval ? ax2 : x2, fy2 = inval ? ay2 : y2;
    bool valid = (fx2 > fx1 + 1.f) && (fy2 > fy1 + 1.f);

    const int m = p * 27 + a;
    scores[(size_t)n * MM + m] = valid ? logit : -INFINITY;
    float4 bx = make_float4(fx1, fy1, fx2, fy2);
    *(float4*)&boxes[((size_t)n * MM + m) * 4] = bx;
}

// ---------------------------------------------------------------------------
// Exact per-image top-100 (desc score, ties -> lowest index) + gather.
// One block of 1024 per image. Radix-select on sign-flipped float keys.
// ---------------------------------------------------------------------------
__device__ inline unsigned ordf(float f)
{
    unsigned u = __float_as_uint(f);
    return (u & 0x80000000u) ? ~u : (u | 0x80000000u);
}

__global__ void topk_props(const float* __restrict__ scores,
                           const float* __restrict__ boxes,
                           float* __restrict__ props)
{
    const int n = blockIdx.x;
    const int tid = threadIdx.x;
    const float* sc = scores + (size_t)n * MM;

    __shared__ unsigned hist[256];
    __shared__ unsigned u_prefix, u_need, cnt;
    __shared__ unsigned long long selk[100];
    __shared__ unsigned wave_tot[16];

    if (tid == 0) { u_prefix = 0; u_need = 100; cnt = 0; }
    __syncthreads();

    // 4x8-bit radix select for the 100th-largest key
    for (int pass = 0; pass < 4; ++pass) {
        if (tid < 256) hist[tid] = 0;
        __syncthreads();
        unsigned pf = u_prefix;
        int shift = 24 - pass * 8;
        for (int i = tid; i < MM; i += 1024) {
            unsigned o = ordf(sc[i]);
            bool match = (pass == 0) || ((o >> (shift + 8)) == (pf >> (shift + 8)));
            if (match) atomicAdd(&hist[(o >> shift) & 255u], 1u);
        }
        __syncthreads();
        if (tid == 0) {
            unsigned nd = u_need;
            int b = 255;
            for (;;) {
                unsigned cb = hist[b];
                if (nd <= cb || b == 0) break;
                nd -= cb;
                --b;
            }
            u_need = nd;
            u_prefix = pf | ((unsigned)b << shift);
        }
        __syncthreads();
    }
    const unsigned T = u_prefix;
    const int need = (int)u_need;     // how many ==T entries to take (lowest indices)
    const int cgt = 100 - need;       // count of strictly-greater entries

    // phase A: collect all keys strictly greater than T (exactly cgt of them)
    for (int i = tid; i < MM; i += 1024) {
        unsigned o = ordf(sc[i]);
        if (o > T) {
            unsigned pz = atomicAdd(&cnt, 1u);
            selk[pz] = ((unsigned long long)o << 32) | (unsigned long long)(~(unsigned)i);
        }
    }
    __syncthreads();

    // phase B: collect `need` lowest-index entries equal to T, in index order
    unsigned hv = 0;
    for (int base = 0; base < MM; base += 1024) {
        int i = base + tid;           // MM % 1024 == 0
        unsigned o = ordf(sc[i]);
        bool f = (o == T);
        unsigned long long bal = __ballot(f);
        if ((tid & 63) == 0) wave_tot[tid >> 6] = (unsigned)__popcll(bal);
        __syncthreads();
        unsigned wbase = 0, tot = 0;
        int wv = tid >> 6;
        for (int w2 = 0; w2 < 16; ++w2) {
            unsigned cw = wave_tot[w2];
            tot += cw;
            if (w2 < wv) wbase += cw;
        }
        if (f) {
            unsigned rk = hv + wbase +
                          (unsigned)__popcll(bal & ((1ull << (tid & 63)) - 1ull));
            if (rk < (unsigned)need)
                selk[cgt + rk] =
                    ((unsigned long long)o << 32) | (unsigned long long)(~(unsigned)i);
        }
        hv += tot;
        __syncthreads();
        if (hv >= (unsigned)need) break;
    }
    __syncthreads();

    // rank-sort 100 elements (distinct keys) and emit props
    if (tid < 100) {
        unsigned long long k = selk[tid];
        int rank = 0;
        for (int j = 0; j < 100; ++j) rank += (selk[j] > k) ? 1 : 0;
        unsigned idx = ~(unsigned)(k & 0xFFFFFFFFull);
        const float* bx = boxes + ((size_t)n * MM + idx) * 4;
        float x1 = bx[0], y1 = bx[1], x2 = bx[2], y2 = bx[3];
        bool v = (x2 > x1 + 1.f) && (y2 > y1 + 1.f);
        float* o = props + ((size_t)n * 100 + rank) * 5;
        o[0] = v ? (float)n : 0.f;
        o[1] = v ? x1 : 0.f;
        o[2] = v ? y1 : 0.f;
        o[3] = v ? x2 : 0.f;
        o[4] = v ? y2 : 0.f;
    }
}

// ---------------------------------------------------------------------------
extern "C" void kernel_launch(void* const* d_in, const int* in_sizes, int n_in,
                              void* d_out, int out_size, void* d_ws, size_t ws_size,
                              hipStream_t stream)
{
    const float* p4 = (const float*)d_in[0];
    const float* w1 = (const float*)d_in[1];
    const float* b1 = (const float*)d_in[2];
    const float* w2 = (const float*)d_in[3];
    const float* b2 = (const float*)d_in[4];
    const float* wc = (const float*)d_in[5];
    const float* bc = (const float*)d_in[6];
    const float* wb = (const float*)d_in[7];
    const float* bb = (const float*)d_in[8];

    float* out   = (float*)d_out;
    float* props = out;            // [8,100,5] = 4000 floats
    float* feat  = out + 4000;     // [8,256,64,64]

    char* ws = (char*)d_ws;
    float* feat1  = (float*)ws;                              // 33,554,432 B
    float* tmp    = (float*)ws;                              // reuse after conv2
    float* scores = (float*)(ws + 33554432);                 // 3,538,944 B
    float* boxesb = (float*)(ws + 33554432 + 3538944);       // 14,155,776 B

    conv3x3_relu<<<512, 256, 0, stream>>>(p4, w1, b1, feat1);
    conv3x3_relu<<<512, 256, 0, stream>>>(feat1, w2, b2, feat);
    conv1x1_kernel<<<512, 256, 0, stream>>>(feat, wc, bc, wb, bb, tmp);
    dim3 g2(432, 8);
    boxes_kernel<<<g2, 256, 0, stream>>>(tmp, scores, boxesb);
    topk_props<<<8, 1024, 0, stream>>>(scores, boxesb, props);
}

// Round 4
// 1308.407 us; speedup vs baseline: 1.4197x; 1.4197x over previous
//
#include <hip/hip_runtime.h>
#include <hip/hip_bf16.h>
#include <math.h>

// Problem constants
#define NN 8
#define CH 256
#define HH 64
#define WW 64
#define AA 27
#define KK 100
#define MM (HH * WW * AA)   // 110592 per image

typedef __attribute__((ext_vector_type(8))) short short8v;
typedef __attribute__((ext_vector_type(4))) float float4v;

#define S1ELEM 8921088ull          // 8*66*66*256 elems per split array
#define WTELEM 589824ull           // 9*256*256 elems per weight split

// ---------------------------------------------------------------------------
// zero halo borders of the 6 padded NHWC bf16 arrays (3 input splits + 3 feat1
// splits). 6 arrays * 8 n * 260 border pixels * 32 ci-chunks = 399360 chunks.
// ---------------------------------------------------------------------------
__global__ void zero_halo(__hip_bfloat16* a3, __hip_bfloat16* f1)
{
    int g = blockIdx.x * 256 + threadIdx.x;       // exactly 399360
    int arr = g / 66560;
    int rem = g - arr * 66560;
    int n = rem / 8320;
    int rem2 = rem - n * 8320;
    int b = rem2 >> 5;
    int q = rem2 & 31;
    int hp, wp;
    if (b < 66)       { hp = 0;        wp = b; }
    else if (b < 132) { hp = 65;       wp = b - 66; }
    else if (b < 196) { hp = b - 131;  wp = 0; }
    else              { hp = b - 195;  wp = 65; }
    __hip_bfloat16* base = (arr < 3) ? (a3 + (size_t)arr * S1ELEM)
                                     : (f1 + (size_t)(arr - 3) * S1ELEM);
    short8v z = {0, 0, 0, 0, 0, 0, 0, 0};
    *(short8v*)(base + (((size_t)n * 66 + hp) * 66 + wp) * 256 + q * 8) = z;
}

// ---------------------------------------------------------------------------
// split fp32 -> 3-way bf16 (h + m + l reconstructs to ~2^-24 rel)
// ---------------------------------------------------------------------------
__device__ inline void split3(float x, __hip_bfloat16& h, __hip_bfloat16& m,
                              __hip_bfloat16& l)
{
    h = __float2bfloat16(x);
    float r = x - __bfloat162float(h);
    m = __float2bfloat16(r);
    float r2 = r - __bfloat162float(m);
    l = __float2bfloat16(r2);
}

// ---------------------------------------------------------------------------
// p4 NCHW fp32 -> padded NHWC bf16 x3 splits. Tile 64ci x 64pix via LDS.
// grid = n(8) * ptile(64 rows) * citile(4); block 256.
// ---------------------------------------------------------------------------
__global__ __launch_bounds__(256)
void prep_in(const float* __restrict__ in, __hip_bfloat16* __restrict__ a3)
{
    __shared__ float s_t[64][65];
    const int tid = threadIdx.x;
    const int ct = blockIdx.x & 3;          // ci tile
    const int row = (blockIdx.x >> 2) & 63; // image row (= pixel tile of 64)
    const int n = blockIdx.x >> 8;
    const int ci0 = ct * 64;

    for (int i = tid; i < 64 * 64; i += 256) {
        int ci = i >> 6, px = i & 63;
        s_t[ci][px] = in[((size_t)(n * 256 + ci0 + ci) << 12) + (row << 6) + px];
    }
    __syncthreads();
    for (int i = tid; i < 64 * 64; i += 256) {
        int px = i >> 6, ci = i & 63;
        float x = s_t[ci][px];
        __hip_bfloat16 h, m, l;
        split3(x, h, m, l);
        size_t base = (((size_t)n * 66 + row + 1) * 66 + px + 1) * 256 + ci0 + ci;
        a3[base] = h;
        a3[base + S1ELEM] = m;
        a3[base + 2 * S1ELEM] = l;
    }
}

// ---------------------------------------------------------------------------
// w (Co,Ci,3,3) fp32 -> wT3[split][tap][co][ci] bf16. 65536 threads.
// ---------------------------------------------------------------------------
__global__ __launch_bounds__(256)
void prep_w(const float* __restrict__ w, __hip_bfloat16* __restrict__ wT3)
{
    int t = blockIdx.x * 256 + threadIdx.x;   // 65536
    int co = t >> 8, ci = t & 255;
    const float* src = w + (size_t)t * 9;
#pragma unroll
    for (int tap = 0; tap < 9; ++tap) {
        __hip_bfloat16 h, m, l;
        split3(src[tap], h, m, l);
        size_t base = ((size_t)tap * 256 + co) * 256 + ci;
        wT3[base] = h;
        wT3[base + WTELEM] = m;
        wT3[base + 2 * WTELEM] = l;
    }
}

// ---------------------------------------------------------------------------
// MFMA 3x3 conv, implicit GEMM, bf16 3-way-split x 6 passes.
// Block: 256 thr (4 waves). Tile: 4 rows x 64 cols x 64 couts; wave = 1 row.
// Grid: n(8) * rowtile(16) * cogroup(4) = 512.
// MODE 0: out = relu(conv)+bias -> padded NHWC bf16 x3 (for next conv)
// MODE 1: out = relu(conv)+bias -> NCHW fp32 (d_out feat)
// ---------------------------------------------------------------------------
template <int MODE>
__global__ __launch_bounds__(256, 2)
void conv_mfma(const __hip_bfloat16* __restrict__ a3,
               const __hip_bfloat16* __restrict__ wT3,
               const float* __restrict__ bias,
               __hip_bfloat16* __restrict__ outb,
               float* __restrict__ outf)
{
    __shared__ __align__(16) __hip_bfloat16 slab[6 * 66 * 32];  // 25344 B

    const int tid = threadIdx.x;
    const int lane = tid & 63, w = tid >> 6;
    const int l15 = lane & 15, l4 = lane >> 4;
    const int bid = blockIdx.x;
    const int cg = bid & 3, rt = (bid >> 2) & 15, n = bid >> 6;
    const int co0 = cg * 64;

    float4v acc[4][4];
#pragma unroll
    for (int p = 0; p < 4; ++p)
#pragma unroll
        for (int ct = 0; ct < 4; ++ct) acc[p][ct] = (float4v){0.f, 0.f, 0.f, 0.f};

    for (int chunk = 0; chunk < 8; ++chunk) {
        const int ci0 = chunk * 32;
        for (int as = 0; as < 3; ++as) {
            __syncthreads();
            // stage 6 rows x 66 cols x 32 ci of split `as` into LDS
            {
                const __hip_bfloat16* src = a3 + (size_t)as * S1ELEM +
                    ((size_t)(n * 66 + rt * 4) * 66) * 256 + ci0;
#pragma unroll
                for (int it = 0; it < 7; ++it) {
                    int c = it * 256 + tid;
                    if (c < 1584) {
                        int r = c / 264;
                        int rem = c - r * 264;
                        int col = rem >> 2, q = rem & 3;
                        short8v v = *(const short8v*)(src + ((size_t)r * 66 + col) * 256 + q * 8);
                        *(short8v*)(slab + c * 8) = v;
                    }
                }
            }
            __syncthreads();
            const int nb = 3 - as;
#pragma unroll
            for (int tap = 0; tap < 9; ++tap) {
                const int dy = tap / 3, dx = tap % 3;
                short8v af[4];
#pragma unroll
                for (int p = 0; p < 4; ++p)
                    af[p] = *(const short8v*)(slab +
                        ((w + dy) * 66 + p * 16 + l15 + dx) * 32 + l4 * 8);
                const __hip_bfloat16* wp0 = wT3 +
                    ((size_t)tap * 256 + co0 + l15) * 256 + ci0 + l4 * 8;
                for (int bs = 0; bs < nb; ++bs) {
                    const __hip_bfloat16* wp = wp0 + (size_t)bs * WTELEM;
#pragma unroll
                    for (int ct = 0; ct < 4; ++ct) {
                        short8v bf = *(const short8v*)(wp + (size_t)ct * 16 * 256);
                        acc[0][ct] = __builtin_amdgcn_mfma_f32_16x16x32_bf16(af[0], bf, acc[0][ct], 0, 0, 0);
                        acc[1][ct] = __builtin_amdgcn_mfma_f32_16x16x32_bf16(af[1], bf, acc[1][ct], 0, 0, 0);
                        acc[2][ct] = __builtin_amdgcn_mfma_f32_16x16x32_bf16(af[2], bf, acc[2][ct], 0, 0, 0);
                        acc[3][ct] = __builtin_amdgcn_mfma_f32_16x16x32_bf16(af[3], bf, acc[3][ct], 0, 0, 0);
                    }
                }
            }
        }
    }

    // epilogue
    float bco[4];
#pragma unroll
    for (int ct = 0; ct < 4; ++ct) bco[ct] = bias[co0 + ct * 16 + l15];
    const int hrow = rt * 4 + w;

    if (MODE == 0) {
#pragma unroll
        for (int p = 0; p < 4; ++p)
#pragma unroll
            for (int ct = 0; ct < 4; ++ct) {
#pragma unroll
                for (int v = 0; v < 4; ++v) {
                    float y = fmaxf(acc[p][ct][v] + bco[ct], 0.f);
                    __hip_bfloat16 h, m, l;
                    split3(y, h, m, l);
                    size_t base = (((size_t)n * 66 + hrow + 1) * 66 +
                                   p * 16 + l4 * 4 + v + 1) * 256 + co0 + ct * 16 + l15;
                    outb[base] = h;
                    outb[base + S1ELEM] = m;
                    outb[base + 2 * S1ELEM] = l;
                }
            }
    } else {
#pragma unroll
        for (int p = 0; p < 4; ++p)
#pragma unroll
            for (int ct = 0; ct < 4; ++ct) {
                float4v y;
#pragma unroll
                for (int v = 0; v < 4; ++v) y[v] = fmaxf(acc[p][ct][v] + bco[ct], 0.f);
                *(float4v*)(outf + ((size_t)(n * 256 + co0 + ct * 16 + l15) << 12) +
                            hrow * 64 + p * 16 + l4 * 4) = y;
            }
    }
}

// ---------------------------------------------------------------------------
// Fused 1x1 convs: 135 output channels (27 logits + 108 deltas). fp32.
// ---------------------------------------------------------------------------
__global__ __launch_bounds__(256, 2)
void conv1x1_kernel(const float* __restrict__ feat, const float* __restrict__ wc,
                    const float* __restrict__ bc, const float* __restrict__ wb,
                    const float* __restrict__ bb, float* __restrict__ tmp)
{
    __shared__ float s_f[64][64];
    __shared__ float s_w[64][137];

    const int tid  = threadIdx.x;
    const int n    = blockIdx.x >> 6;
    const int px0  = (blockIdx.x & 63) << 6;
    const int lane = tid & 63;
    const int g    = tid >> 6;

    float acc[34];
#pragma unroll
    for (int k = 0; k < 34; ++k) acc[k] = 0.f;

    for (int chb = 0; chb < 4; ++chb) {
        const int ci0 = chb << 6;
        __syncthreads();
        for (int i = tid; i < 64 * 64; i += 256) {
            int ci = i >> 6, pp = i & 63;
            s_f[ci][pp] = feat[(((size_t)n * CH + ci0 + ci) << 12) + px0 + pp];
        }
        for (int i = tid; i < 135 * 64; i += 256) {
            int co = i >> 6, ci = i & 63;
            float wv = (co < 27) ? wc[(size_t)co * CH + ci0 + ci]
                                 : wb[(size_t)(co - 27) * CH + ci0 + ci];
            s_w[ci][co] = wv;
        }
        __syncthreads();
        for (int ci = 0; ci < 64; ++ci) {
            float f = s_f[ci][lane];
#pragma unroll
            for (int k = 0; k < 34; ++k) {
                int co = g * 34 + k;
                acc[k] += f * s_w[ci][co < 135 ? co : 134];
            }
        }
    }
#pragma unroll
    for (int k = 0; k < 34; ++k) {
        int co = g * 34 + k;
        if (co < 135) {
            float b = (co < 27) ? bc[co] : bb[co - 27];
            tmp[((size_t)n * 135 + co) * 4096 + px0 + lane] = acc[k] + b;
        }
    }
}

// ---------------------------------------------------------------------------
// Anchors + apply_deltas + validity + score masking. (unchanged, verified)
// ---------------------------------------------------------------------------
__global__ void boxes_kernel(const float* __restrict__ tmp,
                             float* __restrict__ scores, float* __restrict__ boxes)
{
    const int n = blockIdx.y;
    const int i = blockIdx.x * 256 + threadIdx.x;
    const int a = i >> 12;
    const int p = i & 4095;

    const float* t = tmp + (size_t)n * 135 * 4096;
    float logit = t[(size_t)a * 4096 + p];
    float d0 = t[((size_t)(27 + a * 4 + 0)) * 4096 + p];
    float d1 = t[((size_t)(27 + a * 4 + 1)) * 4096 + p];
    float d2 = t[((size_t)(27 + a * 4 + 2)) * 4096 + p];
    float d3 = t[((size_t)(27 + a * 4 + 3)) * 4096 + p];

    const int hh = p >> 6, ww = p & 63;
    const int si = a / 9, ri = (a / 3) % 3, sci = a % 3;

    double s  = (si == 0) ? 32.0 : (si == 1 ? 64.0 : 128.0);
    double r  = (ri == 0) ? 0.5 : (ri == 1 ? 1.0 : 2.0);
    double sv = (sci == 0) ? 1.0 : (sci == 1 ? pow(2.0, 1.0 / 3.0) : pow(2.0, 2.0 / 3.0));
    double sq = sqrt(r);
    float wa = (float)fmax(s * sv * sq, 1.0);
    float ha = (float)fmax(s * sv / sq, 1.0);
    float bx1 = -0.5f * wa, by1 = -0.5f * ha, bx2 = 0.5f * wa, by2 = 0.5f * ha;

    float sx = ((float)ww + 0.5f) * 4.0f;
    float sy = ((float)hh + 0.5f) * 4.0f;
    float ax1 = fmaxf(bx1 + sx, 0.f);
    float ay1 = fmaxf(by1 + sy, 0.f);
    float ax2 = fminf(fmaxf(bx2 + sx, 0.f), 256.f);
    float ay2 = fminf(fmaxf(by2 + sy, 0.f), 256.f);

    float wdt = ax2 - ax1, hgt = ay2 - ay1;
    float cx = ax1 + 0.5f * wdt, cy = ay1 + 0.5f * hgt;
    float dx = d0 / 10.f, dy = d1 / 10.f, dw = d2 / 5.f, dh = d3 / 5.f;
    float pcx = dx * wdt + cx, pcy = dy * hgt + cy;
    float pw = fmaxf(expf(dw) * wdt, 1.f);
    float ph = fmaxf(expf(dh) * hgt, 1.f);
    float x1 = fminf(fmaxf(pcx - 0.5f * pw, 0.f), 256.f);
    float y1 = fminf(fmaxf(pcy - 0.5f * ph, 0.f), 256.f);
    float x2 = fminf(fmaxf(pcx + 0.5f * pw, 0.f), 256.f);
    float y2 = fminf(fmaxf(pcy + 0.5f * ph, 0.f), 256.f);

    bool inval = ((x2 - x1) < 1.f) || ((y2 - y1) < 1.f);
    float fx1 = inval ? ax1 : x1, fy1 = inval ? ay1 : y1;
    float fx2 = inval ? ax2 : x2, fy2 = inval ? ay2 : y2;
    bool valid = (fx2 > fx1 + 1.f) && (fy2 > fy1 + 1.f);

    const int m = p * 27 + a;
    scores[(size_t)n * MM + m] = valid ? logit : -INFINITY;
    float4 bx = make_float4(fx1, fy1, fx2, fy2);
    *(float4*)&boxes[((size_t)n * MM + m) * 4] = bx;
}

// ---------------------------------------------------------------------------
// Exact per-image top-100 + gather. (unchanged, verified)
// ---------------------------------------------------------------------------
__device__ inline unsigned ordf(float f)
{
    unsigned u = __float_as_uint(f);
    return (u & 0x80000000u) ? ~u : (u | 0x80000000u);
}

__global__ void topk_props(const float* __restrict__ scores,
                           const float* __restrict__ boxes,
                           float* __restrict__ props)
{
    const int n = blockIdx.x;
    const int tid = threadIdx.x;
    const float* sc = scores + (size_t)n * MM;

    __shared__ unsigned hist[256];
    __shared__ unsigned u_prefix, u_need, cnt;
    __shared__ unsigned long long selk[100];
    __shared__ unsigned wave_tot[16];

    if (tid == 0) { u_prefix = 0; u_need = 100; cnt = 0; }
    __syncthreads();

    for (int pass = 0; pass < 4; ++pass) {
        if (tid < 256) hist[tid] = 0;
        __syncthreads();
        unsigned pf = u_prefix;
        int shift = 24 - pass * 8;
        for (int i = tid; i < MM; i += 1024) {
            unsigned o = ordf(sc[i]);
            bool match = (pass == 0) || ((o >> (shift + 8)) == (pf >> (shift + 8)));
            if (match) atomicAdd(&hist[(o >> shift) & 255u], 1u);
        }
        __syncthreads();
        if (tid == 0) {
            unsigned nd = u_need;
            int b = 255;
            for (;;) {
                unsigned cb = hist[b];
                if (nd <= cb || b == 0) break;
                nd -= cb;
                --b;
            }
            u_need = nd;
            u_prefix = pf | ((unsigned)b << shift);
        }
        __syncthreads();
    }
    const unsigned T = u_prefix;
    const int need = (int)u_need;
    const int cgt = 100 - need;

    for (int i = tid; i < MM; i += 1024) {
        unsigned o = ordf(sc[i]);
        if (o > T) {
            unsigned pz = atomicAdd(&cnt, 1u);
            selk[pz] = ((unsigned long long)o << 32) | (unsigned long long)(~(unsigned)i);
        }
    }
    __syncthreads();

    unsigned hv = 0;
    for (int base = 0; base < MM; base += 1024) {
        int i = base + tid;
        unsigned o = ordf(sc[i]);
        bool f = (o == T);
        unsigned long long bal = __ballot(f);
        if ((tid & 63) == 0) wave_tot[tid >> 6] = (unsigned)__popcll(bal);
        __syncthreads();
        unsigned wbase = 0, tot = 0;
        int wv = tid >> 6;
        for (int w2 = 0; w2 < 16; ++w2) {
            unsigned cw = wave_tot[w2];
            tot += cw;
            if (w2 < wv) wbase += cw;
        }
        if (f) {
            unsigned rk = hv + wbase +
                          (unsigned)__popcll(bal & ((1ull << (tid & 63)) - 1ull));
            if (rk < (unsigned)need)
                selk[cgt + rk] =
                    ((unsigned long long)o << 32) | (unsigned long long)(~(unsigned)i);
        }
        hv += tot;
        __syncthreads();
        if (hv >= (unsigned)need) break;
    }
    __syncthreads();

    if (tid < 100) {
        unsigned long long k = selk[tid];
        int rank = 0;
        for (int j = 0; j < 100; ++j) rank += (selk[j] > k) ? 1 : 0;
        unsigned idx = ~(unsigned)(k & 0xFFFFFFFFull);
        const float* bx = boxes + ((size_t)n * MM + idx) * 4;
        float x1 = bx[0], y1 = bx[1], x2 = bx[2], y2 = bx[3];
        bool v = (x2 > x1 + 1.f) && (y2 > y1 + 1.f);
        float* o = props + ((size_t)n * 100 + rank) * 5;
        o[0] = v ? (float)n : 0.f;
        o[1] = v ? x1 : 0.f;
        o[2] = v ? y1 : 0.f;
        o[3] = v ? x2 : 0.f;
        o[4] = v ? y2 : 0.f;
    }
}

// ---------------------------------------------------------------------------
extern "C" void kernel_launch(void* const* d_in, const int* in_sizes, int n_in,
                              void* d_out, int out_size, void* d_ws, size_t ws_size,
                              hipStream_t stream)
{
    const float* p4 = (const float*)d_in[0];
    const float* w1 = (const float*)d_in[1];
    const float* b1 = (const float*)d_in[2];
    const float* w2 = (const float*)d_in[3];
    const float* b2 = (const float*)d_in[4];
    const float* wc = (const float*)d_in[5];
    const float* bc = (const float*)d_in[6];
    const float* wb = (const float*)d_in[7];
    const float* bb = (const float*)d_in[8];

    float* out   = (float*)d_out;
    float* props = out;            // [8,100,5]
    float* feat  = out + 4000;     // [8,256,64,64] NCHW fp32

    char* ws = (char*)d_ws;
    // layout (bytes):
    //   a3   [0, 53,526,528)            3x bf16 padded-NHWC input splits
    //   f1   [53,526,528, 107,053,056)  3x bf16 padded-NHWC feat1 splits
    //   wT1  [107,053,056, 110,592,000)
    //   wT2  [110,592,000, 114,130,944)
    //   tmp/scores/boxes overlay the a3 region (dead after conv1... conv2)
    __hip_bfloat16* a3p = (__hip_bfloat16*)ws;
    __hip_bfloat16* f1p = (__hip_bfloat16*)(ws + 53526528);
    __hip_bfloat16* wt1 = (__hip_bfloat16*)(ws + 107053056);
    __hip_bfloat16* wt2 = (__hip_bfloat16*)(ws + 110592000);
    float* tmp    = (float*)ws;                     // 17,694,720 B
    float* scores = (float*)(ws + 17694720);        //  3,538,944 B
    float* boxesb = (float*)(ws + 21233664);        // 14,155,776 B

    zero_halo<<<1560, 256, 0, stream>>>(a3p, f1p);
    prep_w<<<256, 256, 0, stream>>>(w1, wt1);
    prep_w<<<256, 256, 0, stream>>>(w2, wt2);
    prep_in<<<2048, 256, 0, stream>>>(p4, a3p);
    conv_mfma<0><<<512, 256, 0, stream>>>(a3p, wt1, b1, f1p, nullptr);
    conv_mfma<1><<<512, 256, 0, stream>>>(f1p, wt2, b2, nullptr, feat);
    conv1x1_kernel<<<512, 256, 0, stream>>>(feat, wc, bc, wb, bb, tmp);
    dim3 g2(432, 8);
    boxes_kernel<<<g2, 256, 0, stream>>>(tmp, scores, boxesb);
    topk_props<<<8, 1024, 0, stream>>>(scores, boxesb, props);
}